// Round 15
// baseline (238.712 us; speedup 1.0000x reference)
//
#include <hip/hip_runtime.h>
#include <hip/hip_bf16.h>
#include <math.h>

#define BB 256
#define TT 512
#define DIN 64
#define ZZ 32
#define HH 64
#define NITEMS 8192   // 8 k-levels * 256 batches * 4 wave-slots
#define NBAR 513      // barriers per chain role (verified count)

typedef __attribute__((ext_vector_type(4))) float f32x4;
typedef __attribute__((ext_vector_type(8))) __bf16 bf16x8;
typedef __attribute__((ext_vector_type(4))) __bf16 bf16x4;
typedef __attribute__((ext_vector_type(2))) unsigned int u32x2;
typedef __attribute__((ext_vector_type(4))) unsigned int u32x4;
typedef unsigned long long u64;

union FragU { u32x4 u; bf16x8 b; };
union HalfU { bf16x4 b; u32x2 u; };
union VecU  { f32x4 f; u64 u[2]; };

__device__ __forceinline__ f32x4 mfma16(bf16x8 a, bf16x8 b, f32x4 c) {
  return __builtin_amdgcn_mfma_f32_16x16x32_bf16(a, b, c, 0, 0, 0);
}

__device__ __forceinline__ float elu1(float v) {
  return fminf(v, __expf(v) - 1.f);
}
__device__ __forceinline__ f32x4 elu4(f32x4 v) {
  f32x4 r;
  r.x = elu1(v.x); r.y = elu1(v.y); r.z = elu1(v.z); r.w = elu1(v.w);
  return r;
}

__device__ __forceinline__ bf16x8 pack2(f32x4 a, f32x4 b) {
  bf16x8 r;
  r[0] = (__bf16)a.x; r[1] = (__bf16)a.y; r[2] = (__bf16)a.z; r[3] = (__bf16)a.w;
  r[4] = (__bf16)b.x; r[5] = (__bf16)b.y; r[6] = (__bf16)b.z; r[7] = (__bf16)b.w;
  return r;
}

__device__ __forceinline__ void packhl(f32x4 a, f32x4 b, bf16x8& hi, bf16x8& lo) {
  hi = pack2(a, b);
  f32x4 ra, rb;
  ra.x = (float)hi[0]; ra.y = (float)hi[1]; ra.z = (float)hi[2]; ra.w = (float)hi[3];
  rb.x = (float)hi[4]; rb.y = (float)hi[5]; rb.z = (float)hi[6]; rb.w = (float)hi[7];
  lo = pack2(a - ra, b - rb);
}

__device__ __forceinline__ void packh2(f32x4 v, u32x2& hi, u32x2& lo) {
  HalfU H, L;
  H.b[0] = (__bf16)v.x; H.b[1] = (__bf16)v.y;
  H.b[2] = (__bf16)v.z; H.b[3] = (__bf16)v.w;
  f32x4 r;
  r.x = (float)H.b[0]; r.y = (float)H.b[1];
  r.z = (float)H.b[2]; r.w = (float)H.b[3];
  f32x4 d = v - r;
  L.b[0] = (__bf16)d.x; L.b[1] = (__bf16)d.y;
  L.b[2] = (__bf16)d.z; L.b[3] = (__bf16)d.w;
  hi = H.u; lo = L.u;
}

__device__ __forceinline__ bf16x8 ldw(const float* rowp, int o1, int o2) {
  f32x4 a = *reinterpret_cast<const f32x4*>(rowp + o1);
  f32x4 b = *reinterpret_cast<const f32x4*>(rowp + o2);
  return pack2(a, b);
}
__device__ __forceinline__ void ldw2(const float* rowp, int o1, int o2,
                                     bf16x8& hi, bf16x8& lo) {
  f32x4 a = *reinterpret_cast<const f32x4*>(rowp + o1);
  f32x4 b = *reinterpret_cast<const f32x4*>(rowp + o2);
  packhl(a, b, hi, lo);
}

__device__ __forceinline__ float tanh1(float x) {
  float t = __expf(2.f * x);
  return fmaf(-2.f, __builtin_amdgcn_rcpf(t + 1.f), 1.f);
}
__device__ __forceinline__ f32x4 tanh4(f32x4 v) {
  f32x4 r;
  r.x = tanh1(v.x); r.y = tanh1(v.y); r.z = tanh1(v.z); r.w = tanh1(v.w);
  return r;
}

// raw barrier: waits LDS ops only; vmcnt stays in flight across it.
#define STEP_BARRIER() asm volatile("s_waitcnt lgkmcnt(0)\ns_barrier" ::: "memory")

// async global->LDS, 16B per lane (R7-verified). LDS dest wave-uniform base;
// HW writes lane i at base + i*16. Global src per-lane.
__device__ __forceinline__ void gload16(const float* g, f32x4* l) {
  __builtin_amdgcn_global_load_lds(
      (const __attribute__((address_space(1))) unsigned int*)g,
      (__attribute__((address_space(3))) unsigned int*)l,
      16, 0, 0);
}

// coherence-point (sc1) store/load of 8B, relaxed agent scope.
__device__ __forceinline__ void cp_store8(u64* p, u64 v) {
  __hip_atomic_store(p, v, __ATOMIC_RELAXED, __HIP_MEMORY_SCOPE_AGENT);
}
__device__ __forceinline__ u64 cp_load8(const u64* p) {
  return __hip_atomic_load(p, __ATOMIC_RELAXED, __HIP_MEMORY_SCOPE_AGENT);
}

// chain ch's progress flag: rnn batch (16*ch), row 0 -- never used for data.
__device__ __forceinline__ int* chain_flag(float* rnn, int ch) {
  return (int*)(rnn + (size_t)(ch * 16) * TT * ZZ);
}

// ---------------------------------------------------------------------------
// prep_kernel: P0[b,t] = (bi0+bh0) + x[b,t] @ Wi0^T for all 131072 rows,
// plus flag/counter init (block 0). Verbatim R13.
// ---------------------------------------------------------------------------
__global__ __launch_bounds__(256, 2) void prep_kernel(
    const float* __restrict__ x,
    const float* __restrict__ Wi0,
    const float* __restrict__ bi0, const float* __restrict__ bh0,
    float* __restrict__ p0, float* __restrict__ rnn)
{
  if (blockIdx.x == 0) {
    const int t = threadIdx.x;
    if (t < 16) *chain_flag(rnn, t) = 0;
    if (t == 16) *((int*)(rnn + (size_t)TT * ZZ)) = 0;   // work counter
  }
  const int lane = threadIdx.x & 63;
  const int wv = threadIdx.x >> 6;
  const int q = lane >> 4, c = lane & 15;

  bf16x8 Wh[2][2], Wl[2][2];
  #pragma unroll
  for (int kt = 0; kt < 2; ++kt)
    #pragma unroll
    for (int mt = 0; mt < 2; ++mt)
      ldw2(Wi0 + (16 * mt + c) * 64, 32 * kt + 4 * q, 32 * kt + 16 + 4 * q,
           Wh[kt][mt], Wl[kt][mt]);
  f32x4 B0[2];
  #pragma unroll
  for (int mt = 0; mt < 2; ++mt)
    B0[mt] = *reinterpret_cast<const f32x4*>(bi0 + 16 * mt + 4 * q) +
             *reinterpret_cast<const f32x4*>(bh0 + 16 * mt + 4 * q);

  const unsigned row = blockIdx.x * 64u + (unsigned)wv * 16u + (unsigned)c;
  const float* xp = x + (size_t)row * DIN;
  f32x4 x0 = *reinterpret_cast<const f32x4*>(xp + 4 * q);
  f32x4 x1 = *reinterpret_cast<const f32x4*>(xp + 16 + 4 * q);
  f32x4 x2 = *reinterpret_cast<const f32x4*>(xp + 32 + 4 * q);
  f32x4 x3 = *reinterpret_cast<const f32x4*>(xp + 48 + 4 * q);
  bf16x8 xf0 = pack2(x0, x1), xf1 = pack2(x2, x3);

  float* pout = p0 + (size_t)row * ZZ;
  #pragma unroll
  for (int mt = 0; mt < 2; ++mt) {
    f32x4 a = mfma16(Wh[0][mt], xf0, B0[mt]);
    a = mfma16(Wl[0][mt], xf0, a);
    a = mfma16(Wh[1][mt], xf1, a);
    a = mfma16(Wl[1][mt], xf1, a);
    *reinterpret_cast<f32x4*>(pout + 16 * mt + 4 * q) = a;
  }
}

// ---------------------------------------------------------------------------
// fused_kernel v5: R13 structure with two changes:
// (1) d-wave P0 staged through a dynamic-LDS ring via global_load_lds,
//     8-step double-buffered groups, one vmcnt(0) per group (waits loads
//     issued 8 steps = ~4800 cy earlier) -> P-load latency structurally
//     amortized regardless of MALL contention.
// (2) LDS footprint raised to 56.5 KB (48 KB dynamic) -> <= 2 blocks/CU,
//     preventing chain blocks from stacking 4-per-CU.
// Everything else (e-wave, workers, prep, math) verbatim R13.
// ---------------------------------------------------------------------------
__global__ __launch_bounds__(512, 1) void fused_kernel(
    const float* __restrict__ p0buf,
    const float* __restrict__ Wh0,
    const float* __restrict__ Wi1, const float* __restrict__ Wh1,
    const float* __restrict__ bi1, const float* __restrict__ bh1,
    const float* __restrict__ h0g,
    const float* __restrict__ w1, const float* __restrict__ b1,
    const float* __restrict__ w2, const float* __restrict__ b2,
    const float* __restrict__ w3, const float* __restrict__ b3,
    float* __restrict__ rnn, float* __restrict__ out)
{
  extern __shared__ __align__(16) f32x4 dynring[];   // 48 KB dynamic; ring
                                                     // uses [2 mt][2 buf][8][64]
  __shared__ __align__(16) unsigned int sh[2][4][256];
  const int lane = threadIdx.x & 63;
  const int wv = threadIdx.x >> 6;     // 0..7
  const int q = lane >> 4, c = lane & 15;
  const f32x4 Z4 = {0.f, 0.f, 0.f, 0.f};

  if (blockIdx.x < 16) {
    // =================== RNN chain block ===================
    if (wv >= 4) {           // idle waves: match the chain's 513 barriers
      for (int i = 0; i < NBAR; ++i) STEP_BARRIER();
      return;
    }
    __builtin_amdgcn_s_setprio(1);
    const int ch = blockIdx.x;
    const int b0 = ch * 16;

    const float* pp = p0buf + (size_t)(b0 + c) * TT * ZZ;
    float* pr = rnn + (size_t)(b0 + c) * TT * ZZ;
    float* po = out + (size_t)(b0 + c) * TT * ZZ;
    int* flg = chain_flag(rnn, ch);

    const int mt = wv & 1;
    const int dwoff = lane * 4 + mt * 2;

    if (wv < 2) {
      // ---- d-wave: layer 0, tile mt; LDS-ring P0 staging ----
      bf16x8 W0h, W0l;
      ldw2(Wh0 + (16 * mt + c) * 32, 4 * q, 16 + 4 * q, W0h, W0l);
      const float* ppt = pp + 16 * mt + 4 * q;          // per-lane src base
      f32x4* ring = dynring + mt * (2 * 8 * 64);        // wave-private region

      auto stage_group = [&](int g, int buf) {
        f32x4* dst = ring + buf * (8 * 64);
        #pragma unroll
        for (int i = 0; i < 8; ++i) {
          const int t = 511 - 8 * g - i;
          gload16(ppt + (size_t)t * ZZ, dst + i * 64);
        }
      };

      stage_group(0, 0);
      {
        f32x4 u = *reinterpret_cast<const f32x4*>(h0g + 16 * mt + 4 * q);
        u32x2 hi, lo;
        packh2(u, hi, lo);
        *reinterpret_cast<u32x2*>(&sh[0][0][dwoff]) = hi;
        *reinterpret_cast<u32x2*>(&sh[0][1][dwoff]) = lo;
      }
      asm volatile("s_waitcnt vmcnt(0)" ::: "memory");
      f32x4 Pm = ring[lane];     // buf0 slot0 (t=511)
      STEP_BARRIER();

      int buf = 0;
      #pragma unroll 1
      for (int g = 0; g < 64; ++g) {
        if (g < 63) stage_group(g + 1, buf ^ 1);
        #pragma unroll
        for (int i = 0; i < 8; ++i) {
          const int s = 8 * g + i;
          const int cur = s & 1;
          FragU z0, z1;
          z0.u = *reinterpret_cast<const u32x4*>(&sh[cur][0][lane * 4]);
          z1.u = *reinterpret_cast<const u32x4*>(&sh[cur][1][lane * 4]);
          f32x4 dm = mfma16(W0h, z0.b, Pm);
          f32x4 dl = mfma16(W0l, z0.b, mfma16(W0h, z1.b, Z4));
          if (i < 7)   // prefetch next slot (same buf); latency hides in step
            Pm = ring[buf * (8 * 64) + (i + 1) * 64 + lane];
          f32x4 d = tanh4(dm + dl);
          u32x2 hi, lo;
          packh2(d, hi, lo);
          *reinterpret_cast<u32x2*>(&sh[cur ^ 1][0][dwoff]) = hi;
          *reinterpret_cast<u32x2*>(&sh[cur ^ 1][1][dwoff]) = lo;
          STEP_BARRIER();
        }
        // group boundary: next group's loads (issued 8 steps ago) landed
        asm volatile("s_waitcnt vmcnt(0)" ::: "memory");
        buf ^= 1;
        Pm = ring[buf * (8 * 64) + lane];
      }
    } else {
      // ---- e-wave: layer 1, tile mt; publishes progress (verbatim R13) ----
      bf16x8 W1h0, W1l0, W1h1, W1l1;
      ldw2(Wi1 + (16 * mt + c) * 32, 4 * q, 16 + 4 * q, W1h0, W1l0);
      ldw2(Wh1 + (16 * mt + c) * 32, 4 * q, 16 + 4 * q, W1h1, W1l1);
      f32x4 B1 = *reinterpret_cast<const f32x4*>(bi1 + 16 * mt + 4 * q) +
                 *reinterpret_cast<const f32x4*>(bh1 + 16 * mt + 4 * q);

      STEP_BARRIER();

      {
        f32x4 u = *reinterpret_cast<const f32x4*>(h0g + 32 + 16 * mt + 4 * q);
        u32x2 hi, lo;
        packh2(u, hi, lo);
        *reinterpret_cast<u32x2*>(&sh[1][2][dwoff]) = hi;
        *reinterpret_cast<u32x2*>(&sh[1][3][dwoff]) = lo;
        STEP_BARRIER();
      }

      auto ESTEP = [&](int s) {
        const int cur = s & 1;
        FragU zh0, zl0, zh1, zl1;
        zh0.u = *reinterpret_cast<const u32x4*>(&sh[cur][0][lane * 4]);
        zl0.u = *reinterpret_cast<const u32x4*>(&sh[cur][1][lane * 4]);
        zh1.u = *reinterpret_cast<const u32x4*>(&sh[cur][2][lane * 4]);
        zl1.u = *reinterpret_cast<const u32x4*>(&sh[cur][3][lane * 4]);
        f32x4 ea = mfma16(W1h1, zh1.b, mfma16(W1h0, zh0.b, B1));
        f32x4 eb = mfma16(W1h1, zl1.b, mfma16(W1h0, zl0.b, Z4));
        f32x4 ec = mfma16(W1l1, zh1.b, mfma16(W1l0, zh0.b, Z4));
        f32x4 e = tanh4(ea + (eb + ec));
        const int t = 511 - s;
        {
          VecU cv; cv.f = e;
          u64* dp = reinterpret_cast<u64*>(
              pr + (size_t)(t + 1) * ZZ + 16 * mt + 4 * q);
          cp_store8(dp, cv.u[0]);
          cp_store8(dp + 1, cv.u[1]);
        }
        if (t == 510) {
          float* pot = po + (size_t)511 * ZZ + 16 * mt + 4 * q;
          *reinterpret_cast<f32x4*>(pot) = e;
        }
        u32x2 hi, lo;
        packh2(e, hi, lo);
        *reinterpret_cast<u32x2*>(&sh[cur ^ 1][2][dwoff]) = hi;
        *reinterpret_cast<u32x2*>(&sh[cur ^ 1][3][dwoff]) = lo;
        const bool upd = ((s & 15) == 0) || (s == 511);
        if (upd) asm volatile("s_waitcnt vmcnt(0)" ::: "memory");
        STEP_BARRIER();
        if (upd && mt == 0 && lane == 0)
          __hip_atomic_store(flg, s, __ATOMIC_RELAXED,
                             __HIP_MEMORY_SCOPE_AGENT);
      };

      #pragma unroll 1
      for (int g = 0; g < 170; ++g) {       // s = 1..510
        ESTEP(1 + 3 * g);
        ESTEP(2 + 3 * g);
        ESTEP(3 + 3 * g);
      }
      ESTEP(511);
    }
    return;
  }

  // =================== ODE worker block (verbatim R13) ===================
  bf16x8 W1[4], W2[2][4], W3[2][2];
  f32x4 BZ1[4], BZ2[4], BZ3[2];
  #pragma unroll
  for (int mt = 0; mt < 4; ++mt) {
    W1[mt] = ldw(w1 + (16 * mt + c) * 32, 4 * q, 16 + 4 * q);
    BZ1[mt] = *reinterpret_cast<const f32x4*>(b1 + 16 * mt + 4 * q);
    BZ2[mt] = *reinterpret_cast<const f32x4*>(b2 + 16 * mt + 4 * q);
  }
  #pragma unroll
  for (int kt = 0; kt < 2; ++kt)
    #pragma unroll
    for (int mt = 0; mt < 4; ++mt)
      W2[kt][mt] = ldw(w2 + (16 * mt + c) * 64, 32 * kt + 4 * q, 32 * kt + 16 + 4 * q);
  #pragma unroll
  for (int kt = 0; kt < 2; ++kt)
    #pragma unroll
    for (int mt = 0; mt < 2; ++mt)
      W3[kt][mt] = ldw(w3 + (16 * mt + c) * 64, 32 * kt + 4 * q, 32 * kt + 16 + 4 * q);
  #pragma unroll
  for (int mt = 0; mt < 2; ++mt)
    BZ3[mt] = *reinterpret_cast<const f32x4*>(b3 + 16 * mt + 4 * q);

  auto feval = [&](bf16x8 xf, f32x4& o0, f32x4& o1) {
    f32x4 a[4];
    #pragma unroll
    for (int mt = 0; mt < 4; ++mt) a[mt] = mfma16(W1[mt], xf, BZ1[mt]);
    #pragma unroll
    for (int mt = 0; mt < 4; ++mt) a[mt] = elu4(a[mt]);
    bf16x8 h10 = pack2(a[0], a[1]), h11 = pack2(a[2], a[3]);
    f32x4 g[4];
    #pragma unroll
    for (int mt = 0; mt < 4; ++mt)
      g[mt] = mfma16(W2[1][mt], h11, mfma16(W2[0][mt], h10, BZ2[mt]));
    #pragma unroll
    for (int mt = 0; mt < 4; ++mt) g[mt] = elu4(g[mt]);
    bf16x8 h20 = pack2(g[0], g[1]), h21 = pack2(g[2], g[3]);
    o0 = mfma16(W3[1][0], h21, mfma16(W3[0][0], h20, BZ3[0]));
    o1 = mfma16(W3[1][1], h21, mfma16(W3[0][1], h20, BZ3[1]));
  };

  int* ctr = (int*)(rnn + (size_t)TT * ZZ);   // batch 1 row 0 (never data)
  const float hs = 0.01f;

  for (;;) {
    int n0 = 0;
    if (lane == 0)
      n0 = __hip_atomic_fetch_add(ctr, 1, __ATOMIC_RELAXED,
                                  __HIP_MEMORY_SCOPE_AGENT);
    const int n = __shfl(n0, 0);
    if (n >= NITEMS) break;

    const int k7 = n >> 10;            // 0..7, high-t' first
    const int rem = n & 1023;
    const int bb = rem >> 2;           // batch
    const int widx = rem & 3;          // wave slot within k-level
    const int tp = 510 - (64 * k7 + 16 * widx + c);   // may be -1 (1 lane)
    const int ch = bb >> 4;
    int need = 16 + 64 * k7 + 16 * widx;
    if (need > 511) need = 511;

    int* flg = chain_flag(rnn, ch);
    while (__hip_atomic_load(flg, __ATOMIC_RELAXED,
                             __HIP_MEMORY_SCOPE_AGENT) < need)
      __builtin_amdgcn_s_sleep(32);

    const int tpc = tp < 0 ? 0 : tp;
    const u64* sp = reinterpret_cast<const u64*>(
        rnn + ((size_t)bb * TT + tpc + 1) * ZZ);
    VecU c0, c1;
    c0.u[0] = cp_load8(sp + 2 * q);
    c0.u[1] = cp_load8(sp + 2 * q + 1);
    c1.u[0] = cp_load8(sp + 8 + 2 * q);
    c1.u[1] = cp_load8(sp + 8 + 2 * q + 1);
    f32x4 y0 = c0.f;
    f32x4 y1 = c1.f;

    f32x4 k0, k1, ks0, ks1;
    #pragma unroll 1
    for (int it = 0; it < 9; ++it) {
      feval(pack2(y0, y1), k0, k1);
      ks0 = k0; ks1 = k1;
      feval(pack2(y0 + (0.5f * hs) * k0, y1 + (0.5f * hs) * k1), k0, k1);
      ks0 += 2.f * k0; ks1 += 2.f * k1;
      feval(pack2(y0 + (0.5f * hs) * k0, y1 + (0.5f * hs) * k1), k0, k1);
      ks0 += 2.f * k0; ks1 += 2.f * k1;
      feval(pack2(y0 + hs * k0, y1 + hs * k1), k0, k1);
      y0 += (hs / 6.f) * (ks0 + k0);
      y1 += (hs / 6.f) * (ks1 + k1);
    }

    if (tp >= 0) {
      float* dstp = out + ((size_t)bb * TT + tp) * ZZ;
      *reinterpret_cast<f32x4*>(dstp + 4 * q) = y0;
      *reinterpret_cast<f32x4*>(dstp + 16 + 4 * q) = y1;
    }
  }
}

// ---------------------------------------------------------------------------
extern "C" void kernel_launch(void* const* d_in, const int* in_sizes, int n_in,
                              void* d_out, int out_size, void* d_ws, size_t ws_size,
                              hipStream_t stream) {
  const float* x   = (const float*)d_in[0];
  const float* Wi0 = (const float*)d_in[1];
  const float* Wh0 = (const float*)d_in[2];
  const float* bi0 = (const float*)d_in[3];
  const float* bh0 = (const float*)d_in[4];
  const float* Wi1 = (const float*)d_in[5];
  const float* Wh1 = (const float*)d_in[6];
  const float* bi1 = (const float*)d_in[7];
  const float* bh1 = (const float*)d_in[8];
  const float* h0  = (const float*)d_in[9];
  const float* w1  = (const float*)d_in[10];
  const float* b1  = (const float*)d_in[11];
  const float* w2  = (const float*)d_in[12];
  const float* b2  = (const float*)d_in[13];
  const float* w3  = (const float*)d_in[14];
  const float* b3  = (const float*)d_in[15];
  float* out = (float*)d_out;
  float* rnn = (float*)d_ws;      // B*T*Z fp32 scratch; row 0 of selected
                                  // batches doubles as sync flags/counter
  float* p0  = (float*)d_out;     // d_out doubles as P0 scratch (disjoint
                                  // from fused-kernel out writes, proven)

  prep_kernel<<<2048, 256, 0, stream>>>(x, Wi0, bi0, bh0, p0, rnn);
  // 48 KB dynamic LDS: P0 ring (32 KB used) + footprint pad -> <=2 blocks/CU
  fused_kernel<<<256, 512, 48 * 1024, stream>>>(
      p0, Wh0, Wi1, Wh1, bi1, bh1, h0,
      w1, b1, w2, b2, w3, b3, rnn, out);
}

// Round 16
// 223.945 us; speedup vs baseline: 1.0659x; 1.0659x over previous
//
#include <hip/hip_runtime.h>
#include <hip/hip_bf16.h>
#include <math.h>

#define BB 256
#define TT 512
#define DIN 64
#define ZZ 32
#define HH 64
#define NITEMS 8192   // 8 k-levels * 256 batches * 4 wave-slots
#define NBAR 513      // barriers per chain role (verified count)
#define SHROW 3072    // inflated row: LDS = 2*4*3072*4B = 96KB -> 1 block/CU

typedef __attribute__((ext_vector_type(4))) float f32x4;
typedef __attribute__((ext_vector_type(8))) __bf16 bf16x8;
typedef __attribute__((ext_vector_type(4))) __bf16 bf16x4;
typedef __attribute__((ext_vector_type(2))) unsigned int u32x2;
typedef __attribute__((ext_vector_type(4))) unsigned int u32x4;
typedef unsigned long long u64;

union FragU { u32x4 u; bf16x8 b; };
union HalfU { bf16x4 b; u32x2 u; };
union VecU  { f32x4 f; u64 u[2]; };

__device__ __forceinline__ f32x4 mfma16(bf16x8 a, bf16x8 b, f32x4 c) {
  return __builtin_amdgcn_mfma_f32_16x16x32_bf16(a, b, c, 0, 0, 0);
}

__device__ __forceinline__ float elu1(float v) {
  return fminf(v, __expf(v) - 1.f);
}
__device__ __forceinline__ f32x4 elu4(f32x4 v) {
  f32x4 r;
  r.x = elu1(v.x); r.y = elu1(v.y); r.z = elu1(v.z); r.w = elu1(v.w);
  return r;
}

__device__ __forceinline__ bf16x8 pack2(f32x4 a, f32x4 b) {
  bf16x8 r;
  r[0] = (__bf16)a.x; r[1] = (__bf16)a.y; r[2] = (__bf16)a.z; r[3] = (__bf16)a.w;
  r[4] = (__bf16)b.x; r[5] = (__bf16)b.y; r[6] = (__bf16)b.z; r[7] = (__bf16)b.w;
  return r;
}

__device__ __forceinline__ void packhl(f32x4 a, f32x4 b, bf16x8& hi, bf16x8& lo) {
  hi = pack2(a, b);
  f32x4 ra, rb;
  ra.x = (float)hi[0]; ra.y = (float)hi[1]; ra.z = (float)hi[2]; ra.w = (float)hi[3];
  rb.x = (float)hi[4]; rb.y = (float)hi[5]; rb.z = (float)hi[6]; rb.w = (float)hi[7];
  lo = pack2(a - ra, b - rb);
}

__device__ __forceinline__ void packh2(f32x4 v, u32x2& hi, u32x2& lo) {
  HalfU H, L;
  H.b[0] = (__bf16)v.x; H.b[1] = (__bf16)v.y;
  H.b[2] = (__bf16)v.z; H.b[3] = (__bf16)v.w;
  f32x4 r;
  r.x = (float)H.b[0]; r.y = (float)H.b[1];
  r.z = (float)H.b[2]; r.w = (float)H.b[3];
  f32x4 d = v - r;
  L.b[0] = (__bf16)d.x; L.b[1] = (__bf16)d.y;
  L.b[2] = (__bf16)d.z; L.b[3] = (__bf16)d.w;
  hi = H.u; lo = L.u;
}

__device__ __forceinline__ bf16x8 ldw(const float* rowp, int o1, int o2) {
  f32x4 a = *reinterpret_cast<const f32x4*>(rowp + o1);
  f32x4 b = *reinterpret_cast<const f32x4*>(rowp + o2);
  return pack2(a, b);
}
__device__ __forceinline__ void ldw2(const float* rowp, int o1, int o2,
                                     bf16x8& hi, bf16x8& lo) {
  f32x4 a = *reinterpret_cast<const f32x4*>(rowp + o1);
  f32x4 b = *reinterpret_cast<const f32x4*>(rowp + o2);
  packhl(a, b, hi, lo);
}

__device__ __forceinline__ float tanh1(float x) {
  float t = __expf(2.f * x);
  return fmaf(-2.f, __builtin_amdgcn_rcpf(t + 1.f), 1.f);
}
__device__ __forceinline__ f32x4 tanh4(f32x4 v) {
  f32x4 r;
  r.x = tanh1(v.x); r.y = tanh1(v.y); r.z = tanh1(v.z); r.w = tanh1(v.w);
  return r;
}

// raw barrier: waits LDS ops only; vmcnt stays in flight across it.
#define STEP_BARRIER() asm volatile("s_waitcnt lgkmcnt(0)\ns_barrier" ::: "memory")

// coherence-point (sc1) store/load of 8B, relaxed agent scope.
__device__ __forceinline__ void cp_store8(u64* p, u64 v) {
  __hip_atomic_store(p, v, __ATOMIC_RELAXED, __HIP_MEMORY_SCOPE_AGENT);
}
__device__ __forceinline__ u64 cp_load8(const u64* p) {
  return __hip_atomic_load(p, __ATOMIC_RELAXED, __HIP_MEMORY_SCOPE_AGENT);
}

// chain ch's progress flag: rnn batch (16*ch), row 0 -- never used for data.
__device__ __forceinline__ int* chain_flag(float* rnn, int ch) {
  return (int*)(rnn + (size_t)(ch * 16) * TT * ZZ);
}

// ---------------------------------------------------------------------------
// prep_kernel: P0[b,t] = (bi0+bh0) + x[b,t] @ Wi0^T for all 131072 rows,
// plus flag/counter init (block 0). Verbatim R13.
// ---------------------------------------------------------------------------
__global__ __launch_bounds__(256, 2) void prep_kernel(
    const float* __restrict__ x,
    const float* __restrict__ Wi0,
    const float* __restrict__ bi0, const float* __restrict__ bh0,
    float* __restrict__ p0, float* __restrict__ rnn)
{
  if (blockIdx.x == 0) {
    const int t = threadIdx.x;
    if (t < 16) *chain_flag(rnn, t) = 0;
    if (t == 16) *((int*)(rnn + (size_t)TT * ZZ)) = 0;   // work counter
  }
  const int lane = threadIdx.x & 63;
  const int wv = threadIdx.x >> 6;
  const int q = lane >> 4, c = lane & 15;

  bf16x8 Wh[2][2], Wl[2][2];
  #pragma unroll
  for (int kt = 0; kt < 2; ++kt)
    #pragma unroll
    for (int mt = 0; mt < 2; ++mt)
      ldw2(Wi0 + (16 * mt + c) * 64, 32 * kt + 4 * q, 32 * kt + 16 + 4 * q,
           Wh[kt][mt], Wl[kt][mt]);
  f32x4 B0[2];
  #pragma unroll
  for (int mt = 0; mt < 2; ++mt)
    B0[mt] = *reinterpret_cast<const f32x4*>(bi0 + 16 * mt + 4 * q) +
             *reinterpret_cast<const f32x4*>(bh0 + 16 * mt + 4 * q);

  const unsigned row = blockIdx.x * 64u + (unsigned)wv * 16u + (unsigned)c;
  const float* xp = x + (size_t)row * DIN;
  f32x4 x0 = *reinterpret_cast<const f32x4*>(xp + 4 * q);
  f32x4 x1 = *reinterpret_cast<const f32x4*>(xp + 16 + 4 * q);
  f32x4 x2 = *reinterpret_cast<const f32x4*>(xp + 32 + 4 * q);
  f32x4 x3 = *reinterpret_cast<const f32x4*>(xp + 48 + 4 * q);
  bf16x8 xf0 = pack2(x0, x1), xf1 = pack2(x2, x3);

  float* pout = p0 + (size_t)row * ZZ;
  #pragma unroll
  for (int mt = 0; mt < 2; ++mt) {
    f32x4 a = mfma16(Wh[0][mt], xf0, B0[mt]);
    a = mfma16(Wl[0][mt], xf0, a);
    a = mfma16(Wh[1][mt], xf1, a);
    a = mfma16(Wl[1][mt], xf1, a);
    *reinterpret_cast<f32x4*>(pout + 16 * mt + 4 * q) = a;
  }
}

// ---------------------------------------------------------------------------
// fused_kernel v6: R13 source verbatim, except the LDS exchange buffer is
// inflated to 96 KB so at most ONE block fits per CU. With exactly 256
// blocks on 256 CUs, every block (chain or worker) owns its CU: chain waves
// never share SIMD issue slots with anything -> in-situ chain should run at
// its standalone ~595 cy/step.
// ---------------------------------------------------------------------------
__global__ __launch_bounds__(512, 1) void fused_kernel(
    const float* __restrict__ p0buf,
    const float* __restrict__ Wh0,
    const float* __restrict__ Wi1, const float* __restrict__ Wh1,
    const float* __restrict__ bi1, const float* __restrict__ bh1,
    const float* __restrict__ h0g,
    const float* __restrict__ w1, const float* __restrict__ b1,
    const float* __restrict__ w2, const float* __restrict__ b2,
    const float* __restrict__ w3, const float* __restrict__ b3,
    float* __restrict__ rnn, float* __restrict__ out)
{
  // 2*4*SHROW u32 = 96 KB static LDS: only [.][.][0..255] is ever touched;
  // the size exists purely to cap occupancy at 1 block/CU.
  __shared__ __align__(16) unsigned int sh[2][4][SHROW];
  const int lane = threadIdx.x & 63;
  const int wv = threadIdx.x >> 6;     // 0..7
  const int q = lane >> 4, c = lane & 15;
  const f32x4 Z4 = {0.f, 0.f, 0.f, 0.f};

  if (blockIdx.x < 16) {
    // =================== RNN chain block ===================
    if (wv >= 4) {           // idle waves: match the chain's 513 barriers
      for (int i = 0; i < NBAR; ++i) STEP_BARRIER();
      return;
    }
    __builtin_amdgcn_s_setprio(1);
    const int ch = blockIdx.x;
    const int b0 = ch * 16;

    const float* pp = p0buf + (size_t)(b0 + c) * TT * ZZ;
    float* pr = rnn + (size_t)(b0 + c) * TT * ZZ;
    float* po = out + (size_t)(b0 + c) * TT * ZZ;
    int* flg = chain_flag(rnn, ch);

    const int mt = wv & 1;
    const int dwoff = lane * 4 + mt * 2;

    if (wv < 2) {
      // ---- d-wave: layer 0, tile mt ----  (1 + 512 barriers)
      bf16x8 W0h, W0l;
      ldw2(Wh0 + (16 * mt + c) * 32, 4 * q, 16 + 4 * q, W0h, W0l);
      const float* ppt = pp + 16 * mt + 4 * q;

      {
        f32x4 u = *reinterpret_cast<const f32x4*>(h0g + 16 * mt + 4 * q);
        u32x2 hi, lo;
        packh2(u, hi, lo);
        *reinterpret_cast<u32x2*>(&sh[0][0][dwoff]) = hi;
        *reinterpret_cast<u32x2*>(&sh[0][1][dwoff]) = lo;
      }
      f32x4 Pa = *reinterpret_cast<const f32x4*>(ppt + (size_t)511 * ZZ);
      f32x4 Pb = *reinterpret_cast<const f32x4*>(ppt + (size_t)510 * ZZ);
      f32x4 Pc = *reinterpret_cast<const f32x4*>(ppt + (size_t)509 * ZZ);

      STEP_BARRIER();

      auto DSTEP = [&](int s, f32x4& Pm) {
        const int cur = s & 1;
        FragU z0, z1;
        z0.u = *reinterpret_cast<const u32x4*>(&sh[cur][0][lane * 4]);
        z1.u = *reinterpret_cast<const u32x4*>(&sh[cur][1][lane * 4]);
        f32x4 dm = mfma16(W0h, z0.b, Pm);
        f32x4 dl = mfma16(W0l, z0.b, mfma16(W0h, z1.b, Z4));
        {
          const int t = 511 - s;
          const int tl = t >= 3 ? t - 3 : 0;
          Pm = *reinterpret_cast<const f32x4*>(ppt + (size_t)tl * ZZ);
        }
        f32x4 d = tanh4(dm + dl);
        u32x2 hi, lo;
        packh2(d, hi, lo);
        *reinterpret_cast<u32x2*>(&sh[cur ^ 1][0][dwoff]) = hi;
        *reinterpret_cast<u32x2*>(&sh[cur ^ 1][1][dwoff]) = lo;
        STEP_BARRIER();
      };

      DSTEP(0, Pa);
      #pragma unroll 1
      for (int g = 0; g < 170; ++g) {
        DSTEP(1 + 3 * g, Pb);
        DSTEP(2 + 3 * g, Pc);
        DSTEP(3 + 3 * g, Pa);
      }
      DSTEP(511, Pb);
    } else {
      // ---- e-wave: layer 1, tile mt; publishes progress ----  (2+511 barriers)
      bf16x8 W1h0, W1l0, W1h1, W1l1;
      ldw2(Wi1 + (16 * mt + c) * 32, 4 * q, 16 + 4 * q, W1h0, W1l0);
      ldw2(Wh1 + (16 * mt + c) * 32, 4 * q, 16 + 4 * q, W1h1, W1l1);
      f32x4 B1 = *reinterpret_cast<const f32x4*>(bi1 + 16 * mt + 4 * q) +
                 *reinterpret_cast<const f32x4*>(bh1 + 16 * mt + 4 * q);

      STEP_BARRIER();

      {
        f32x4 u = *reinterpret_cast<const f32x4*>(h0g + 32 + 16 * mt + 4 * q);
        u32x2 hi, lo;
        packh2(u, hi, lo);
        *reinterpret_cast<u32x2*>(&sh[1][2][dwoff]) = hi;
        *reinterpret_cast<u32x2*>(&sh[1][3][dwoff]) = lo;
        STEP_BARRIER();
      }

      auto ESTEP = [&](int s) {
        const int cur = s & 1;
        FragU zh0, zl0, zh1, zl1;
        zh0.u = *reinterpret_cast<const u32x4*>(&sh[cur][0][lane * 4]);
        zl0.u = *reinterpret_cast<const u32x4*>(&sh[cur][1][lane * 4]);
        zh1.u = *reinterpret_cast<const u32x4*>(&sh[cur][2][lane * 4]);
        zl1.u = *reinterpret_cast<const u32x4*>(&sh[cur][3][lane * 4]);
        f32x4 ea = mfma16(W1h1, zh1.b, mfma16(W1h0, zh0.b, B1));
        f32x4 eb = mfma16(W1h1, zl1.b, mfma16(W1h0, zl0.b, Z4));
        f32x4 ec = mfma16(W1l1, zh1.b, mfma16(W1l0, zh0.b, Z4));
        f32x4 e = tanh4(ea + (eb + ec));
        const int t = 511 - s;
        // rnn store -> coherence point (sc1), visible to workers w/o fences
        {
          VecU cv; cv.f = e;
          u64* dp = reinterpret_cast<u64*>(
              pr + (size_t)(t + 1) * ZZ + 16 * mt + 4 * q);
          cp_store8(dp, cv.u[0]);
          cp_store8(dp + 1, cv.u[1]);
        }
        if (t == 510) {
          float* pot = po + (size_t)511 * ZZ + 16 * mt + 4 * q;
          *reinterpret_cast<f32x4*>(pot) = e;
        }
        u32x2 hi, lo;
        packh2(e, hi, lo);
        *reinterpret_cast<u32x2*>(&sh[cur ^ 1][2][dwoff]) = hi;
        *reinterpret_cast<u32x2*>(&sh[cur ^ 1][3][dwoff]) = lo;
        const bool upd = ((s & 15) == 0) || (s == 511);
        if (upd) asm volatile("s_waitcnt vmcnt(0)" ::: "memory");
        STEP_BARRIER();
        if (upd && mt == 0 && lane == 0)
          __hip_atomic_store(flg, s, __ATOMIC_RELAXED,
                             __HIP_MEMORY_SCOPE_AGENT);
      };

      #pragma unroll 1
      for (int g = 0; g < 170; ++g) {       // s = 1..510
        ESTEP(1 + 3 * g);
        ESTEP(2 + 3 * g);
        ESTEP(3 + 3 * g);
      }
      ESTEP(511);
    }
    return;
  }

  // =================== ODE worker block (verbatim R13) ===================
  bf16x8 W1[4], W2[2][4], W3[2][2];
  f32x4 BZ1[4], BZ2[4], BZ3[2];
  #pragma unroll
  for (int mt = 0; mt < 4; ++mt) {
    W1[mt] = ldw(w1 + (16 * mt + c) * 32, 4 * q, 16 + 4 * q);
    BZ1[mt] = *reinterpret_cast<const f32x4*>(b1 + 16 * mt + 4 * q);
    BZ2[mt] = *reinterpret_cast<const f32x4*>(b2 + 16 * mt + 4 * q);
  }
  #pragma unroll
  for (int kt = 0; kt < 2; ++kt)
    #pragma unroll
    for (int mt = 0; mt < 4; ++mt)
      W2[kt][mt] = ldw(w2 + (16 * mt + c) * 64, 32 * kt + 4 * q, 32 * kt + 16 + 4 * q);
  #pragma unroll
  for (int kt = 0; kt < 2; ++kt)
    #pragma unroll
    for (int mt = 0; mt < 2; ++mt)
      W3[kt][mt] = ldw(w3 + (16 * mt + c) * 64, 32 * kt + 4 * q, 32 * kt + 16 + 4 * q);
  #pragma unroll
  for (int mt = 0; mt < 2; ++mt)
    BZ3[mt] = *reinterpret_cast<const f32x4*>(b3 + 16 * mt + 4 * q);

  auto feval = [&](bf16x8 xf, f32x4& o0, f32x4& o1) {
    f32x4 a[4];
    #pragma unroll
    for (int mt = 0; mt < 4; ++mt) a[mt] = mfma16(W1[mt], xf, BZ1[mt]);
    #pragma unroll
    for (int mt = 0; mt < 4; ++mt) a[mt] = elu4(a[mt]);
    bf16x8 h10 = pack2(a[0], a[1]), h11 = pack2(a[2], a[3]);
    f32x4 g[4];
    #pragma unroll
    for (int mt = 0; mt < 4; ++mt)
      g[mt] = mfma16(W2[1][mt], h11, mfma16(W2[0][mt], h10, BZ2[mt]));
    #pragma unroll
    for (int mt = 0; mt < 4; ++mt) g[mt] = elu4(g[mt]);
    bf16x8 h20 = pack2(g[0], g[1]), h21 = pack2(g[2], g[3]);
    o0 = mfma16(W3[1][0], h21, mfma16(W3[0][0], h20, BZ3[0]));
    o1 = mfma16(W3[1][1], h21, mfma16(W3[0][1], h20, BZ3[1]));
  };

  int* ctr = (int*)(rnn + (size_t)TT * ZZ);   // batch 1 row 0 (never data)
  const float hs = 0.01f;

  for (;;) {
    int n0 = 0;
    if (lane == 0)
      n0 = __hip_atomic_fetch_add(ctr, 1, __ATOMIC_RELAXED,
                                  __HIP_MEMORY_SCOPE_AGENT);
    const int n = __shfl(n0, 0);
    if (n >= NITEMS) break;

    const int k7 = n >> 10;            // 0..7, high-t' first
    const int rem = n & 1023;
    const int bb = rem >> 2;           // batch
    const int widx = rem & 3;          // wave slot within k-level
    const int tp = 510 - (64 * k7 + 16 * widx + c);   // may be -1 (1 lane)
    const int ch = bb >> 4;
    int need = 16 + 64 * k7 + 16 * widx;
    if (need > 511) need = 511;

    int* flg = chain_flag(rnn, ch);
    while (__hip_atomic_load(flg, __ATOMIC_RELAXED,
                             __HIP_MEMORY_SCOPE_AGENT) < need)
      __builtin_amdgcn_s_sleep(32);

    const int tpc = tp < 0 ? 0 : tp;
    const u64* sp = reinterpret_cast<const u64*>(
        rnn + ((size_t)bb * TT + tpc + 1) * ZZ);
    VecU c0, c1;
    c0.u[0] = cp_load8(sp + 2 * q);
    c0.u[1] = cp_load8(sp + 2 * q + 1);
    c1.u[0] = cp_load8(sp + 8 + 2 * q);
    c1.u[1] = cp_load8(sp + 8 + 2 * q + 1);
    f32x4 y0 = c0.f;
    f32x4 y1 = c1.f;

    f32x4 k0, k1, ks0, ks1;
    #pragma unroll 1
    for (int it = 0; it < 9; ++it) {
      feval(pack2(y0, y1), k0, k1);
      ks0 = k0; ks1 = k1;
      feval(pack2(y0 + (0.5f * hs) * k0, y1 + (0.5f * hs) * k1), k0, k1);
      ks0 += 2.f * k0; ks1 += 2.f * k1;
      feval(pack2(y0 + (0.5f * hs) * k0, y1 + (0.5f * hs) * k1), k0, k1);
      ks0 += 2.f * k0; ks1 += 2.f * k1;
      feval(pack2(y0 + hs * k0, y1 + hs * k1), k0, k1);
      y0 += (hs / 6.f) * (ks0 + k0);
      y1 += (hs / 6.f) * (ks1 + k1);
    }

    if (tp >= 0) {
      float* dstp = out + ((size_t)bb * TT + tp) * ZZ;
      *reinterpret_cast<f32x4*>(dstp + 4 * q) = y0;
      *reinterpret_cast<f32x4*>(dstp + 16 + 4 * q) = y1;
    }
  }
}

// ---------------------------------------------------------------------------
extern "C" void kernel_launch(void* const* d_in, const int* in_sizes, int n_in,
                              void* d_out, int out_size, void* d_ws, size_t ws_size,
                              hipStream_t stream) {
  const float* x   = (const float*)d_in[0];
  const float* Wi0 = (const float*)d_in[1];
  const float* Wh0 = (const float*)d_in[2];
  const float* bi0 = (const float*)d_in[3];
  const float* bh0 = (const float*)d_in[4];
  const float* Wi1 = (const float*)d_in[5];
  const float* Wh1 = (const float*)d_in[6];
  const float* bi1 = (const float*)d_in[7];
  const float* bh1 = (const float*)d_in[8];
  const float* h0  = (const float*)d_in[9];
  const float* w1  = (const float*)d_in[10];
  const float* b1  = (const float*)d_in[11];
  const float* w2  = (const float*)d_in[12];
  const float* b2  = (const float*)d_in[13];
  const float* w3  = (const float*)d_in[14];
  const float* b3  = (const float*)d_in[15];
  float* out = (float*)d_out;
  float* rnn = (float*)d_ws;      // B*T*Z fp32 scratch; row 0 of selected
                                  // batches doubles as sync flags/counter
  float* p0  = (float*)d_out;     // d_out doubles as P0 scratch (disjoint
                                  // from fused-kernel out writes, proven)

  prep_kernel<<<2048, 256, 0, stream>>>(x, Wi0, bi0, bh0, p0, rnn);
  // 96 KB static LDS per block -> exactly 1 block/CU -> 256 blocks on 256
  // CUs, chain blocks fully isolated from worker issue traffic.
  fused_kernel<<<256, 512, 0, stream>>>(p0, Wh0, Wi1, Wh1, bi1, bh1, h0,
                                        w1, b1, w2, b2, w3, b3, rnn, out);
}